// Round 3
// baseline (357.547 us; speedup 1.0000x reference)
//
#include <hip/hip_runtime.h>
#include <hip/hip_fp16.h>

#define N_NODES 100000
#define N_EDGES 1600000
#define D 64

#define EPB 4096                        // edges per pre_k hist block
#define NBLKA 391                       // ceil(1.6e6/4096)
#define X_OCTETS (N_NODES * D / 8)      // 800000
#define CVT_BLKS ((X_OCTETS + 2048 + 511) / 512)  // 1567
#define SCAN_BLKS ((N_NODES + 255) / 256)         // 391
#define AGB (N_NODES / 32)              // 3125 fused agg+gemm blocks (exact)

typedef _Float16 half8 __attribute__((ext_vector_type(8)));
typedef float floatx4 __attribute__((ext_vector_type(4)));

// ---------- fp32 -> fp16 convert helpers ----------

__device__ __forceinline__ uint4 pack8h(float4 a, float4 b) {
    __half2 h0, h1, h2, h3;
    h0.x = __float2half(a.x); h0.y = __float2half(a.y);
    h1.x = __float2half(a.z); h1.y = __float2half(a.w);
    h2.x = __float2half(b.x); h2.y = __float2half(b.y);
    h3.x = __float2half(b.z); h3.y = __float2half(b.w);
    uint4 pk;
    pk.x = *(unsigned int*)&h0; pk.y = *(unsigned int*)&h1;
    pk.z = *(unsigned int*)&h2; pk.w = *(unsigned int*)&h3;
    return pk;
}

// ---------- merged: degree histogram (blocks < NBLKA) + fp32->fp16 converts ----------
// Degree via direct global atomicAdd: 1.6M increments spread over 100k
// L2-resident counters (~16/addr over the whole kernel) — low contention,
// no barriers, replaces the 391-block LDS bucket-histogram machinery.

__global__ void pre_k(const float* __restrict__ x,
                      const float* __restrict__ W1l, const float* __restrict__ W1r,
                      const float* __restrict__ W2l, const float* __restrict__ W2r,
                      const int* __restrict__ dst, int* __restrict__ deg,
                      __half* __restrict__ x16,
                      __half* __restrict__ o1l, __half* __restrict__ o1r,
                      __half* __restrict__ o2l, __half* __restrict__ o2r) {
    int t = threadIdx.x;  // 512
    if (blockIdx.x < NBLKA) {
        int base = blockIdx.x * EPB;
#pragma unroll
        for (int r = 0; r < 8; r++) {
            int idx = base + r * 512 + t;
            if (idx < N_EDGES) atomicAdd(&deg[dst[idx]], 1);
        }
        return;
    }
    int i = (blockIdx.x - NBLKA) * 512 + t;
    const float* s;
    __half* d;
    int j;
    if (i < X_OCTETS) {
        s = x; d = x16; j = i * 8;
    } else {
        int k = i - X_OCTETS;
        if (k >= 2048) return;
        int arr = k >> 9;  // 512 octets per 4096-elem matrix
        j = (k & 511) * 8;
        s = (arr == 0) ? W1l : (arr == 1) ? W1r : (arr == 2) ? W2l : W2r;
        d = (arr == 0) ? o1l : (arr == 1) ? o1r : (arr == 2) ? o2l : o2r;
    }
    float4 a = *(const float4*)&s[j];
    float4 b = *(const float4*)&s[j + 4];
    *(uint4*)&d[j] = pack8h(a, b);
}

// ---------- two-level scan of deg[100000] ----------

__global__ void scan1_k(int* __restrict__ data, int* __restrict__ bsums, int n) {
    __shared__ int sm[256];
    int i = blockIdx.x * 256 + threadIdx.x;
    int v = (i < n) ? data[i] : 0;
    sm[threadIdx.x] = v;
    __syncthreads();
    for (int off = 1; off < 256; off <<= 1) {
        int t = (threadIdx.x >= off) ? sm[threadIdx.x - off] : 0;
        __syncthreads();
        sm[threadIdx.x] += t;
        __syncthreads();
    }
    if (i < n) data[i] = sm[threadIdx.x] - v;  // exclusive within block
    if (threadIdx.x == 255) bsums[blockIdx.x] = sm[255];
}

__global__ void scan2_k(int* __restrict__ bsums, int nb) {
    __shared__ int sm[1024];
    int v = (threadIdx.x < nb) ? bsums[threadIdx.x] : 0;
    sm[threadIdx.x] = v;
    __syncthreads();
    for (int off = 1; off < 1024; off <<= 1) {
        int t = (threadIdx.x >= off) ? sm[threadIdx.x - off] : 0;
        __syncthreads();
        sm[threadIdx.x] += t;
        __syncthreads();
    }
    if (threadIdx.x < nb) bsums[threadIdx.x] = sm[threadIdx.x];
}

// ---------- finalize: absolute row_ptr + scatter cursor ----------

__global__ void fin_k(const int* __restrict__ deg, const int* __restrict__ bsums,
                      int* __restrict__ row_ptr, int* __restrict__ cur) {
    int i = blockIdx.x * 256 + threadIdx.x;
    if (i < N_NODES) {
        int v = deg[i];
        if (blockIdx.x > 0) v += bsums[blockIdx.x - 1];
        row_ptr[i] = v;
        cur[i] = v;
    }
    if (blockIdx.x == 0 && threadIdx.x == 0) row_ptr[N_NODES] = N_EDGES;
}

// ---------- scatter: CSR adj in one fully-parallel pass ----------
// Within-node order is arbitrary (atomic slot allocation) — mean aggregation
// is order-insensitive up to fp16 rounding (~1-2 ulp; measured 4x headroom).

__global__ void scat_k(const int4* __restrict__ src4, const int4* __restrict__ dst4,
                       int* __restrict__ cur, int* __restrict__ adj) {
    int i = blockIdx.x * 256 + threadIdx.x;
    if (i >= N_EDGES / 4) return;
    int4 s = src4[i];
    int4 d = dst4[i];
    adj[atomicAdd(&cur[d.x], 1)] = s.x;
    adj[atomicAdd(&cur[d.y], 1)] = s.y;
    adj[atomicAdd(&cur[d.z], 1)] = s.z;
    adj[atomicAdd(&cur[d.w], 1)] = s.w;
}

// ---------- FUSED aggregation + linear (per layer, one kernel) ----------
// Block = 256 threads = 32 nodes (N_NODES = 3125*32 exactly, no tail).
// Phase 1 (agg): 8-lane groups gather+accumulate packed fp16, compute fp32
// mean, pack to fp16 into a 4 KB LDS tile (XOR-swizzled 16B chunks so the
// MFMA-phase read is bank-even). Phase 2 (gemm): each wave owns a 16-feature
// strip; A-frags for lin_l come from the LDS mean tile, A-frags for lin_r
// straight from global feat16 rows; B-frags in 16 VGPRs loaded once.

__device__ __forceinline__ void addp(__half2* a, uint4 v) {
    const __half2* h = (const __half2*)&v;
    a[0] = __hadd2(a[0], h[0]);
    a[1] = __hadd2(a[1], h[1]);
    a[2] = __hadd2(a[2], h[2]);
    a[3] = __hadd2(a[3], h[3]);
}

__global__ void agg_gemm_k(const __half* __restrict__ feat16,  // gather table == Fp
                           const int* __restrict__ row_ptr,
                           const int* __restrict__ adj,
                           const __half* __restrict__ Wl16,    // [64][64]
                           const __half* __restrict__ Wr16,
                           const float* __restrict__ bl,
                           float* __restrict__ out32,          // nullable
                           __half* __restrict__ out16,         // nullable
                           int do_relu) {
    __shared__ __half mt[32 * 64];  // mean tile, chunk-swizzled
    int t = threadIdx.x;
    int lane = t & 63;
    int w = t >> 6;
    int fp = lane & 7;
    int gl = lane & 56;             // base lane of 8-lane group
    int nloc = w * 8 + (lane >> 3); // 0..31
    int node = blockIdx.x * 32 + nloc;
    const uint4* f16 = (const uint4*)feat16;

    // B-frags + bias (latency hides under the gather loop)
    int fcol = lane & 15;
    int quad = lane >> 4;
    int f = w * 16 + fcol;
    half8 b0 = *(const half8*)(Wl16 + (size_t)f * 64 + quad * 8);
    half8 b1 = *(const half8*)(Wl16 + (size_t)f * 64 + 32 + quad * 8);
    half8 b2 = *(const half8*)(Wr16 + (size_t)f * 64 + quad * 8);
    half8 b3 = *(const half8*)(Wr16 + (size_t)f * 64 + 32 + quad * 8);
    float bias = bl[f];

    // ---- phase 1: mean aggregation ----
    int beg = row_ptr[node];
    int end = row_ptr[node + 1];
    __half2 z; z.x = __float2half(0.f); z.y = z.x;
    __half2 aA[4] = {z, z, z, z};
    __half2 aB[4] = {z, z, z, z};

    int e = beg;
    for (; e + 7 < end; e += 8) {
        int am = adj[e + fp];  // lane fp owns edge e+fp: one aligned dword load
        int n0 = __shfl(am, gl + 0);
        int n1 = __shfl(am, gl + 1);
        int n2 = __shfl(am, gl + 2);
        int n3 = __shfl(am, gl + 3);
        int n4 = __shfl(am, gl + 4);
        int n5 = __shfl(am, gl + 5);
        int n6 = __shfl(am, gl + 6);
        int n7 = __shfl(am, gl + 7);
        uint4 v0 = f16[(size_t)n0 * 8 + fp];
        uint4 v1 = f16[(size_t)n1 * 8 + fp];
        uint4 v2 = f16[(size_t)n2 * 8 + fp];
        uint4 v3 = f16[(size_t)n3 * 8 + fp];
        uint4 v4 = f16[(size_t)n4 * 8 + fp];
        uint4 v5 = f16[(size_t)n5 * 8 + fp];
        uint4 v6 = f16[(size_t)n6 * 8 + fp];
        uint4 v7 = f16[(size_t)n7 * 8 + fp];
        addp(aA, v0); addp(aB, v1); addp(aA, v2); addp(aB, v3);
        addp(aA, v4); addp(aB, v5); addp(aA, v6); addp(aB, v7);
    }
    if (e + 3 < end) {
        uint4 v0 = f16[(size_t)adj[e] * 8 + fp];
        uint4 v1 = f16[(size_t)adj[e + 1] * 8 + fp];
        uint4 v2 = f16[(size_t)adj[e + 2] * 8 + fp];
        uint4 v3 = f16[(size_t)adj[e + 3] * 8 + fp];
        addp(aA, v0); addp(aB, v1); addp(aA, v2); addp(aB, v3);
        e += 4;
    }
    for (; e < end; e++) addp(aA, f16[(size_t)adj[e] * 8 + fp]);

    int dg = end - beg;
    float inv = (dg > 1) ? 1.0f / (float)dg : 1.0f;
    float2 s0 = __half22float2(aA[0]), s1 = __half22float2(aA[1]);
    float2 s2 = __half22float2(aA[2]), s3 = __half22float2(aA[3]);
    float2 t0 = __half22float2(aB[0]), t1 = __half22float2(aB[1]);
    float2 t2 = __half22float2(aB[2]), t3 = __half22float2(aB[3]);
    float4 o0, o1;
    o0.x = (s0.x + t0.x) * inv; o0.y = (s0.y + t0.y) * inv;
    o0.z = (s1.x + t1.x) * inv; o0.w = (s1.y + t1.y) * inv;
    o1.x = (s2.x + t2.x) * inv; o1.y = (s2.y + t2.y) * inv;
    o1.z = (s3.x + t3.x) * inv; o1.w = (s3.y + t3.y) * inv;
    *(uint4*)&mt[(size_t)nloc * 64 + 8 * (fp ^ (nloc & 7))] = pack8h(o0, o1);
    __syncthreads();

    // ---- phase 2: out = mean @ Wl^T + bl + feat @ Wr^T ----
#pragma unroll
    for (int tile = 0; tile < 2; tile++) {
        int row = tile * 16 + fcol;
        half8 a0 = *(const half8*)&mt[(size_t)row * 64 + 8 * (quad ^ (row & 7))];
        half8 a1 = *(const half8*)&mt[(size_t)row * 64 + 8 * ((4 + quad) ^ (row & 7))];
        size_t frow = ((size_t)blockIdx.x * 32 + row) * 64 + quad * 8;
        half8 a2 = *(const half8*)(feat16 + frow);
        half8 a3 = *(const half8*)(feat16 + frow + 32);

        floatx4 acc = {0.f, 0.f, 0.f, 0.f};
        acc = __builtin_amdgcn_mfma_f32_16x16x32_f16(a0, b0, acc, 0, 0, 0);
        acc = __builtin_amdgcn_mfma_f32_16x16x32_f16(a1, b1, acc, 0, 0, 0);
        acc = __builtin_amdgcn_mfma_f32_16x16x32_f16(a2, b2, acc, 0, 0, 0);
        acc = __builtin_amdgcn_mfma_f32_16x16x32_f16(a3, b3, acc, 0, 0, 0);

#pragma unroll
        for (int r = 0; r < 4; r++) {
            int node2 = blockIdx.x * 32 + tile * 16 + quad * 4 + r;
            float v = acc[r] + bias;
            if (do_relu) v = fmaxf(v, 0.f);
            if (out32) out32[(size_t)node2 * 64 + f] = v;
            if (out16) out16[(size_t)node2 * 64 + f] = __float2half(v);
        }
    }
}

extern "C" void kernel_launch(void* const* d_in, const int* in_sizes, int n_in,
                              void* d_out, int out_size, void* d_ws, size_t ws_size,
                              hipStream_t stream) {
    const float* x   = (const float*)d_in[0];
    const int*   ei  = (const int*)d_in[1];   // [2, E]: src then dst
    const float* W1l = (const float*)d_in[2];
    const float* b1l = (const float*)d_in[3];
    const float* W1r = (const float*)d_in[4];
    const float* W2l = (const float*)d_in[5];
    const float* b2l = (const float*)d_in[6];
    const float* W2r = (const float*)d_in[7];
    float* out = (float*)d_out;

    const int* src = ei;
    const int* dst = ei + N_EDGES;

    // workspace layout (~33 MB)
    __half* x16   = (__half*)d_ws;                        // N*D halves
    __half* h16   = x16 + (size_t)N_NODES * D;            // N*D
    __half* w1l16 = h16 + (size_t)N_NODES * D;            // 4096
    __half* w1r16 = w1l16 + 4096;
    __half* w2l16 = w1r16 + 4096;
    __half* w2r16 = w2l16 + 4096;
    int*   deg    = (int*)(w2r16 + 4096);                 // N_NODES
    int*   bsums  = deg + N_NODES;                        // 512
    int*   row_ptr = bsums + 512;                         // N_NODES+1
    int*   cur    = row_ptr + N_NODES + 1;                // N_NODES
    int*   adj    = cur + N_NODES;                        // N_EDGES

    // zero the degree counters (graph-capture-safe async memset)
    hipMemsetAsync(deg, 0, (size_t)N_NODES * sizeof(int), stream);

    // converts + degree histogram (one kernel, disjoint block ranges)
    pre_k<<<NBLKA + CVT_BLKS, 512, 0, stream>>>(x, W1l, W1r, W2l, W2r, dst, deg,
                                                x16, w1l16, w1r16, w2l16, w2r16);

    // row_ptr = exclusive scan of degrees; cur = scatter cursor
    scan1_k<<<SCAN_BLKS, 256, 0, stream>>>(deg, bsums, N_NODES);
    scan2_k<<<1, 1024, 0, stream>>>(bsums, SCAN_BLKS);
    fin_k<<<SCAN_BLKS, 256, 0, stream>>>(deg, bsums, row_ptr, cur);

    // CSR adjacency in one fully-parallel pass
    scat_k<<<(N_EDGES / 4 + 255) / 256, 256, 0, stream>>>(
        (const int4*)src, (const int4*)dst, cur, adj);

    // layer 1: agg(x16) -> h16 (relu)
    agg_gemm_k<<<AGB, 256, 0, stream>>>(x16, row_ptr, adj,
                                        w1l16, w1r16, b1l,
                                        (float*)nullptr, h16, 1);
    // layer 2: agg(h16) -> out (fp32)
    agg_gemm_k<<<AGB, 256, 0, stream>>>(h16, row_ptr, adj,
                                        w2l16, w2r16, b2l,
                                        out, (__half*)nullptr, 0);
}